// Round 3
// baseline (1487.609 us; speedup 1.0000x reference)
//
#include <hip/hip_runtime.h>

#define B_ 128
#define T_ 1000
#define NI 64
#define NH 256
#define DT_ 0.05f
#define GAMMA_ 2.7f
#define EPS_ 4.7f
#define CH 8            // steps buffered per output flush
#define NCH 125         // T_/CH
#define BTH (128*1000*256)

// One block per batch element; persistent scan over all T steps.
// 512 threads: oct = tid&7 owns k-rows 32*oct..32*oct+31; cg = tid>>3 owns
// columns 4cg..4cg+3 (float4 weights in registers). hy broadcast via LDS,
// 8-way k-split partials reduced with shfl_xor(1,2,4); lanes oct<4 own one
// column each for the state update and stores.
__global__ __launch_bounds__(512, 2) void ron_scan(
    const float* __restrict__ x, const float* __restrict__ h2h,
    const float* __restrict__ x2h, float* __restrict__ out)
{
    // hyb: 8 sections of 32 floats, stride 36 -> section starts at banks
    // 0,4,8,...,28; per dword-phase all 32 banks serve 1 address (broadcast).
    // xts: 8 sections of 8 floats, stride 12 -> starts 0,12,24,4,16,28,8,20.
    __shared__ __align__(16) float hyb[2][288];
    __shared__ __align__(16) float xts[2][CH][96];
    __shared__ __align__(16) float ob[4][CH][NH];   // 8-step output buffer (32 KB)

    const int tid = threadIdx.x;
    const int oct = tid & 7;
    const int cg  = tid >> 3;          // 0..63
    const int b   = blockIdx.x;
    const int myc = 4*cg + oct;        // column owned (valid when oct<4)

    // ---- stage weights into registers (float4 over 4 owned columns) ----
    float4 ha[32], xa[8];
#pragma unroll
    for (int k = 0; k < 32; ++k)
        ha[k] = *(const float4*)&h2h[(32*oct + k)*NH + 4*cg];
#pragma unroll
    for (int k = 0; k < 8; ++k)
        xa[k] = *(const float4*)&x2h[(8*oct + k)*NH + 4*cg];

    if (tid < 288) hyb[0][tid] = 0.0f;
    {   // preload x chunk 0 (8 steps x 64 inputs), stride-12 sections
        int s = tid >> 6, k = tid & 63;
        xts[0][s][k + 4*(k >> 3)] = x[(b*T_ + s)*NI + k];
    }
    __syncthreads();

    float u = 0.f, hz = 0.f, hy = 0.f;
    int pb = 0;

    for (int cb = 0; cb < NCH; ++cb) {
        const int t0 = cb * CH;
        // prefetch next x chunk into a register (landed to LDS at chunk end)
        float xv = 0.f;
        const bool pf = (cb + 1 < NCH);
        if (pf) {
            int s = tid >> 6, k = tid & 63;
            xv = x[(b*T_ + t0 + CH + s)*NI + k];
        }
        const int xb = cb & 1;

#pragma unroll
        for (int tt = 0; tt < CH; ++tt) {
            float4 acc = {0.f, 0.f, 0.f, 0.f};
            const float* hsec = &hyb[pb][36*oct];
#pragma unroll
            for (int k4 = 0; k4 < 8; ++k4) {
                float4 h = *(const float4*)(hsec + 4*k4);
                float4 w0 = ha[4*k4+0], w1 = ha[4*k4+1], w2 = ha[4*k4+2], w3 = ha[4*k4+3];
                acc.x += h.x*w0.x + h.y*w1.x + h.z*w2.x + h.w*w3.x;
                acc.y += h.x*w0.y + h.y*w1.y + h.z*w2.y + h.w*w3.y;
                acc.z += h.x*w0.z + h.y*w1.z + h.z*w2.z + h.w*w3.z;
                acc.w += h.x*w0.w + h.y*w1.w + h.z*w2.w + h.w*w3.w;
            }
            const float* xsec = &xts[xb][tt][12*oct];
#pragma unroll
            for (int k4 = 0; k4 < 2; ++k4) {
                float4 h = *(const float4*)(xsec + 4*k4);
                float4 w0 = xa[4*k4+0], w1 = xa[4*k4+1], w2 = xa[4*k4+2], w3 = xa[4*k4+3];
                acc.x += h.x*w0.x + h.y*w1.x + h.z*w2.x + h.w*w3.x;
                acc.y += h.x*w0.y + h.y*w1.y + h.z*w2.y + h.w*w3.y;
                acc.z += h.x*w0.z + h.y*w1.z + h.z*w2.z + h.w*w3.z;
                acc.w += h.x*w0.w + h.y*w1.w + h.z*w2.w + h.w*w3.w;
            }
            // reduce the 8 k-oct partials within each 8-lane group
            acc.x += __shfl_xor(acc.x, 1); acc.x += __shfl_xor(acc.x, 2); acc.x += __shfl_xor(acc.x, 4);
            acc.y += __shfl_xor(acc.y, 1); acc.y += __shfl_xor(acc.y, 2); acc.y += __shfl_xor(acc.y, 4);
            acc.z += __shfl_xor(acc.z, 1); acc.z += __shfl_xor(acc.z, 2); acc.z += __shfl_xor(acc.z, 4);
            acc.w += __shfl_xor(acc.w, 1); acc.w += __shfl_xor(acc.w, 2); acc.w += __shfl_xor(acc.w, 4);
            const float drv = (oct == 0) ? acc.x : (oct == 1) ? acc.y
                            : (oct == 2) ? acc.z : acc.w;

            // spiking + oscillator update (spike from PRE-update u; u_dot uses OLD hy)
            const float spk = (u > 1.0f) ? 1.0f : 0.0f;
            const float ur  = (u > 1.0f) ? 0.0f : u;
            u  = ur + (drv - ur) * DT_;          // BIAS=0, RC=1
            hz = hz + DT_ * (u - GAMMA_*hy - EPS_*hz);
            hy = hy + DT_ * hz;

            if (oct < 4) {
                hyb[pb ^ 1][36*(myc >> 5) + (myc & 31)] = hy;
                ob[0][tt][myc] = hy;
                ob[1][tt][myc] = hz;
                ob[2][tt][myc] = u;
                ob[3][tt][myc] = spk;
            }
            pb ^= 1;
            __syncthreads();
        }

        if (pf) {   // land prefetched x chunk
            int s = tid >> 6, k = tid & 63;
            xts[xb ^ 1][s][k + 4*(k >> 3)] = xv;
        }

        // flush 8-step output buffer: 2048 float4, coalesced per (array, t) row
        const float* obf = &ob[0][0][0];
#pragma unroll
        for (int r = 0; r < 4; ++r) {
            int j  = r*512 + tid;
            int a  = j >> 9;
            int tt = (j >> 6) & 7;
            int c4 = (j & 63) * 4;
            float4 v = *(const float4*)(obf + 4*j);
            *(float4*)(out + (size_t)a*BTH + ((size_t)b*T_ + t0 + tt)*NH + c4) = v;
        }
        __syncthreads();
    }
}

extern "C" void kernel_launch(void* const* d_in, const int* in_sizes, int n_in,
                              void* d_out, int out_size, void* d_ws, size_t ws_size,
                              hipStream_t stream) {
    const float* x   = (const float*)d_in[0];
    const float* h2h = (const float*)d_in[1];
    const float* x2h = (const float*)d_in[2];
    float* out = (float*)d_out;
    ron_scan<<<B_, 512, 0, stream>>>(x, h2h, x2h, out);
}

// Round 4
// 1144.366 us; speedup vs baseline: 1.2999x; 1.2999x over previous
//
#include <hip/hip_runtime.h>

#define B_ 128
#define T_ 1000
#define NI 64
#define NH 256
#define DT_ 0.05f
#define GAMMA_ 2.7f
#define EPS_ 4.7f
#define CH 8            // steps buffered per output flush
#define NCH 125         // T_/CH
#define BTH (128*1000*256)

// DPP butterfly add: v += value from lane permuted by CTRL (VALU pipe, no LDS).
template <int CTRL>
__device__ __forceinline__ float dppAdd(float v) {
    int x = __builtin_amdgcn_update_dpp(__float_as_int(v), __float_as_int(v),
                                        CTRL, 0xF, 0xF, false);
    return v + __int_as_float(x);
}

// Barrier that drains only LDS (lgkmcnt), NOT vmcnt — keeps the x-prefetch
// global load and the output-flush stores in flight across step barriers.
// All cross-thread hazards in this kernel are LDS-only.
__device__ __forceinline__ void barLds() {
    asm volatile("s_waitcnt lgkmcnt(0)\n\ts_barrier" ::: "memory");
}

// One block per batch element; persistent scan over all T steps.
// 512 threads: oct = tid&7 owns k-rows 32*oct..32*oct+31; cg = tid>>3 owns
// columns 4cg..4cg+3 (float4 weights in registers, explicit fmaf).
// hy broadcast via double-buffered LDS (buffer parity = tt&1, compile-time);
// 8-way k-split partials reduced with DPP xor1/xor2/half-mirror (VALU pipe).
__global__ __launch_bounds__(512, 2) void ron_scan(
    const float* __restrict__ x, const float* __restrict__ h2h,
    const float* __restrict__ x2h, float* __restrict__ out)
{
    // hyb: 8 sections of 32 floats, stride 36 -> per-phase all 32 banks serve
    // one address each (8-way broadcast, conflict-free).
    // xts: 8 sections of 8 floats, stride 12 -> section starts cover all banks.
    __shared__ __align__(16) float hyb[2][288];
    __shared__ __align__(16) float xts[2][CH][96];
    __shared__ __align__(16) float ob2[CH * NH * 4];  // packed (hy,hz,u,spk)

    const int tid = threadIdx.x;
    const int oct = tid & 7;
    const int cg  = tid >> 3;          // 0..63
    const int b   = blockIdx.x;
    const int myc = 4 * cg + oct;      // column owned (valid when oct<4)

    // ---- stage weights into registers (float4 over 4 owned columns) ----
    float4 ha[32], xa[8];
#pragma unroll
    for (int k = 0; k < 32; ++k)
        ha[k] = *(const float4*)&h2h[(32 * oct + k) * NH + 4 * cg];
#pragma unroll
    for (int k = 0; k < 8; ++k)
        xa[k] = *(const float4*)&x2h[(8 * oct + k) * NH + 4 * cg];

    if (tid < 288) hyb[0][tid] = 0.0f;
    {   // preload x chunk 0 (8 steps x 64 inputs), stride-12 sections
        int s = tid >> 6, k = tid & 63;
        xts[0][s][k + 4 * (k >> 3)] = x[(b * T_ + s) * NI + k];
    }
    __syncthreads();

    float u = 0.f, hz = 0.f, hy = 0.f;

    // precomputed LDS pointers (buffer selected by compile-time tt&1)
    const float* const hs0 = &hyb[0][36 * oct];
    const float* const hs1 = &hyb[1][36 * oct];
    float* const hw0 = &hyb[0][36 * (myc >> 5) + (myc & 31)];
    float* const hw1 = &hyb[1][36 * (myc >> 5) + (myc & 31)];
    float* const obw = &ob2[myc * 4];
    const float* const xsb0 = &xts[0][0][12 * oct];
    const float* const xsb1 = &xts[1][0][12 * oct];

    for (int cb = 0; cb < NCH; ++cb) {
        // prefetch next x chunk into a register (landed to LDS at chunk end);
        // stays in flight across the lgkmcnt-only step barriers.
        float xv = 0.f;
        const bool pf = (cb + 1 < NCH);
        if (pf) {
            int s = tid >> 6, k = tid & 63;
            xv = x[(b * T_ + cb * CH + CH + s) * NI + k];
        }
        const float* const xsecb = (cb & 1) ? xsb1 : xsb0;

#pragma unroll
        for (int tt = 0; tt < CH; ++tt) {
            const float* const hsec = (tt & 1) ? hs1 : hs0;
            float ax = 0.f, ay = 0.f, az = 0.f, aw = 0.f;
#pragma unroll
            for (int k4 = 0; k4 < 8; ++k4) {
                float4 h = *(const float4*)(hsec + 4 * k4);
                const float4 w0 = ha[4 * k4 + 0], w1 = ha[4 * k4 + 1];
                const float4 w2 = ha[4 * k4 + 2], w3 = ha[4 * k4 + 3];
                ax = fmaf(h.x, w0.x, ax); ax = fmaf(h.y, w1.x, ax);
                ax = fmaf(h.z, w2.x, ax); ax = fmaf(h.w, w3.x, ax);
                ay = fmaf(h.x, w0.y, ay); ay = fmaf(h.y, w1.y, ay);
                ay = fmaf(h.z, w2.y, ay); ay = fmaf(h.w, w3.y, ay);
                az = fmaf(h.x, w0.z, az); az = fmaf(h.y, w1.z, az);
                az = fmaf(h.z, w2.z, az); az = fmaf(h.w, w3.z, az);
                aw = fmaf(h.x, w0.w, aw); aw = fmaf(h.y, w1.w, aw);
                aw = fmaf(h.z, w2.w, aw); aw = fmaf(h.w, w3.w, aw);
            }
            const float* const xsec = xsecb + tt * 96;
#pragma unroll
            for (int k4 = 0; k4 < 2; ++k4) {
                float4 h = *(const float4*)(xsec + 4 * k4);
                const float4 w0 = xa[4 * k4 + 0], w1 = xa[4 * k4 + 1];
                const float4 w2 = xa[4 * k4 + 2], w3 = xa[4 * k4 + 3];
                ax = fmaf(h.x, w0.x, ax); ax = fmaf(h.y, w1.x, ax);
                ax = fmaf(h.z, w2.x, ax); ax = fmaf(h.w, w3.x, ax);
                ay = fmaf(h.x, w0.y, ay); ay = fmaf(h.y, w1.y, ay);
                ay = fmaf(h.z, w2.y, ay); ay = fmaf(h.w, w3.y, ay);
                az = fmaf(h.x, w0.z, az); az = fmaf(h.y, w1.z, az);
                az = fmaf(h.z, w2.z, az); az = fmaf(h.w, w3.z, az);
                aw = fmaf(h.x, w0.w, aw); aw = fmaf(h.y, w1.w, aw);
                aw = fmaf(h.z, w2.w, aw); aw = fmaf(h.w, w3.w, aw);
            }
            // 8-lane k-reduction on the VALU pipe: xor1, xor2, cross-quad.
            ax = dppAdd<0xB1>(ax); ax = dppAdd<0x4E>(ax); ax = dppAdd<0x141>(ax);
            ay = dppAdd<0xB1>(ay); ay = dppAdd<0x4E>(ay); ay = dppAdd<0x141>(ay);
            az = dppAdd<0xB1>(az); az = dppAdd<0x4E>(az); az = dppAdd<0x141>(az);
            aw = dppAdd<0xB1>(aw); aw = dppAdd<0x4E>(aw); aw = dppAdd<0x141>(aw);
            const float drv = (oct == 0) ? ax : (oct == 1) ? ay
                            : (oct == 2) ? az : aw;

            // spiking + oscillator update (spike from PRE-update u; drv uses OLD hy)
            const float spk = (u > 1.0f) ? 1.0f : 0.0f;
            const float ur  = (u > 1.0f) ? 0.0f : u;
            u  = fmaf(drv - ur, DT_, ur);        // BIAS=0, RC=1
            hz = fmaf(DT_, fmaf(-EPS_, hz, fmaf(-GAMMA_, hy, u)), hz);
            hy = fmaf(DT_, hz, hy);

            if (oct < 4) {
                *((tt & 1) ? hw0 : hw1) = hy;    // write the OTHER buffer
                *(float4*)(obw + tt * NH * 4) = make_float4(hy, hz, u, spk);
            }
            barLds();
        }

        if (pf) {   // land prefetched x chunk into the other xts buffer
            int s = tid >> 6, k = tid & 63;
            xts[(cb & 1) ^ 1][s][k + 4 * (k >> 3)] = xv;
        }

        // flush 8-step packed output buffer: unpack (hy,hz,u,spk) to 4 arrays
#pragma unroll
        for (int r = 0; r < 4; ++r) {
            int idx = r * 512 + tid;
            int tt  = idx >> 8;
            int c   = idx & 255;
            float4 v = *(const float4*)&ob2[idx * 4];
            size_t base = ((size_t)b * T_ + cb * CH + tt) * NH + c;
            out[base]                   = v.x;
            out[(size_t)BTH + base]     = v.y;
            out[(size_t)2 * BTH + base] = v.z;
            out[(size_t)3 * BTH + base] = v.w;
        }
        barLds();
    }
}

extern "C" void kernel_launch(void* const* d_in, const int* in_sizes, int n_in,
                              void* d_out, int out_size, void* d_ws, size_t ws_size,
                              hipStream_t stream) {
    const float* x   = (const float*)d_in[0];
    const float* h2h = (const float*)d_in[1];
    const float* x2h = (const float*)d_in[2];
    float* out = (float*)d_out;
    ron_scan<<<B_, 512, 0, stream>>>(x, h2h, x2h, out);
}

// Round 10
// 1124.755 us; speedup vs baseline: 1.3226x; 1.0174x over previous
//
#include <hip/hip_runtime.h>

#define B_ 128
#define T_ 1000
#define NI 64
#define NH 256
#define DT_ 0.05f
#define GAMMA_ 2.7f
#define EPS_ 4.7f
#define BTH (128u*1000u*256u)

typedef float f2 __attribute__((ext_vector_type(2)));

// DPP move: returns partner lane's value per CTRL (VALU pipe).
template <int CTRL>
__device__ __forceinline__ float dppMov(float v) {
    return __int_as_float(__builtin_amdgcn_update_dpp(
        __float_as_int(v), __float_as_int(v), CTRL, 0xF, 0xF, false));
}

// 8 FMAs as 4 packed v_pk_fma_f32: broadcast h-scalar into 4 column-pair accs.
// (h,h) broadcast should fold to VOP3P op_sel; worst case 1 v_mov.
#define FMA8(hv, w01, w23, w45, w67) {                     \
    const f2 hh = {(hv), (hv)};                            \
    ac01 = __builtin_elementwise_fma(hh, (w01), ac01);     \
    ac23 = __builtin_elementwise_fma(hh, (w23), ac23);     \
    ac45 = __builtin_elementwise_fma(hh, (w45), ac45);     \
    ac67 = __builtin_elementwise_fma(hh, (w67), ac67);     \
}

// One step of the scan. P = LDS buffer parity (compile-time).
// Reads hy from hyb[P], writes new hy to hyb[P^1].
#define STEP(P, tcur) {                                                        \
    const int tn = ((tcur) + 1 < T_) ? (tcur) + 1 : (tcur);                    \
    const float4 xn = *(const float4*)&x[((size_t)bT + tn) * NI + 4 * hex];    \
    const float* hs = (P) ? rs1 : rs0;                                         \
    const float4 h0v = *(const float4*)(hs + 0);                               \
    const float4 h1v = *(const float4*)(hs + 4);                               \
    const float4 h2v = *(const float4*)(hs + 8);                               \
    const float4 h3v = *(const float4*)(hs + 12);                              \
    f2 ac01 = {0.f, 0.f}, ac23 = {0.f, 0.f};                                   \
    f2 ac45 = {0.f, 0.f}, ac67 = {0.f, 0.f};                                   \
    FMA8(h0v.x, ha01[0],  ha23[0],  ha45[0],  ha67[0]);                        \
    FMA8(h0v.y, ha01[1],  ha23[1],  ha45[1],  ha67[1]);                        \
    FMA8(h0v.z, ha01[2],  ha23[2],  ha45[2],  ha67[2]);                        \
    FMA8(h0v.w, ha01[3],  ha23[3],  ha45[3],  ha67[3]);                        \
    FMA8(h1v.x, ha01[4],  ha23[4],  ha45[4],  ha67[4]);                        \
    FMA8(h1v.y, ha01[5],  ha23[5],  ha45[5],  ha67[5]);                        \
    FMA8(h1v.z, ha01[6],  ha23[6],  ha45[6],  ha67[6]);                        \
    FMA8(h1v.w, ha01[7],  ha23[7],  ha45[7],  ha67[7]);                        \
    FMA8(h2v.x, ha01[8],  ha23[8],  ha45[8],  ha67[8]);                        \
    FMA8(h2v.y, ha01[9],  ha23[9],  ha45[9],  ha67[9]);                        \
    FMA8(h2v.z, ha01[10], ha23[10], ha45[10], ha67[10]);                       \
    FMA8(h2v.w, ha01[11], ha23[11], ha45[11], ha67[11]);                       \
    FMA8(h3v.x, ha01[12], ha23[12], ha45[12], ha67[12]);                       \
    FMA8(h3v.y, ha01[13], ha23[13], ha45[13], ha67[13]);                       \
    FMA8(h3v.z, ha01[14], ha23[14], ha45[14], ha67[14]);                       \
    FMA8(h3v.w, ha01[15], ha23[15], ha45[15], ha67[15]);                       \
    FMA8(xcur.x, xa01[0], xa23[0], xa45[0], xa67[0]);                          \
    FMA8(xcur.y, xa01[1], xa23[1], xa45[1], xa67[1]);                          \
    FMA8(xcur.z, xa01[2], xa23[2], xa45[2], xa67[2]);                          \
    FMA8(xcur.w, xa01[3], xa23[3], xa45[3], xa67[3]);                          \
    float a0 = ac01.x, a1 = ac01.y, a2 = ac23.x, a3 = ac23.y;                  \
    float a4 = ac45.x, a5 = ac45.y, a6 = ac67.x, a7 = ac67.y;                  \
    /* L1: xor7 mirror, full butterfly (any cross partner valid pre-select) */ \
    a0 += dppMov<0x141>(a0); a1 += dppMov<0x141>(a1);                          \
    a2 += dppMov<0x141>(a2); a3 += dppMov<0x141>(a3);                          \
    a4 += dppMov<0x141>(a4); a5 += dppMov<0x141>(a5);                          \
    a6 += dppMov<0x141>(a6); a7 += dppMov<0x141>(a7);                          \
    /* L2: xor1 recursive halving (keep col-bit0 == hex-bit0, export other) */ \
    float s0 = (b0 ? a1 : a0) + dppMov<0xB1>(b0 ? a0 : a1);                    \
    float s1 = (b0 ? a3 : a2) + dppMov<0xB1>(b0 ? a2 : a3);                    \
    float s2 = (b0 ? a5 : a4) + dppMov<0xB1>(b0 ? a4 : a5);                    \
    float s3 = (b0 ? a7 : a6) + dppMov<0xB1>(b0 ? a6 : a7);                    \
    /* L3: xor2 halving */                                                     \
    float t0 = (b1 ? s1 : s0) + dppMov<0x4E>(b1 ? s0 : s1);                    \
    float t1 = (b1 ? s3 : s2) + dppMov<0x4E>(b1 ? s2 : s3);                    \
    /* L4: pick col-bit2 slot; xor8 (row_ror:8) full butterfly (dup partner */ \
    /* hex+8 holds the SAME column, other k-half) */                           \
    float drv = b2 ? t1 : t0;                                                  \
    drv += dppMov<0x128>(drv);                                                 \
    /* spiking + oscillator update (spike from PRE-update u) */                \
    const float spk = (u > 1.0f) ? 1.0f : 0.0f;                                \
    const float ur  = (u > 1.0f) ? 0.0f : u;                                   \
    u  = fmaf(drv - ur, DT_, ur);            /* BIAS=0, RC=1 */                \
    hz = fmaf(DT_, fmaf(-EPS_, hz, fmaf(-GAMMA_, hy, u)), hz);                 \
    hy = fmaf(DT_, hz, hy);                                                    \
    if (hex < 8) {                                                             \
        *((P) ? wB : wA) = hy;               /* hy -> buffer P^1 */            \
        const size_t ob = (size_t)(bT + (tcur)) * NH + col;                    \
        out[ob]                    = hy;                                       \
        out[(size_t)BTH + ob]      = hz;                                       \
        out[(size_t)2 * BTH + ob]  = u;                                        \
        out[(size_t)3 * BTH + ob]  = spk;                                      \
    }                                                                          \
    asm volatile("s_waitcnt lgkmcnt(0)\n\ts_barrier" ::: "memory");            \
    xcur = xn;                                                                 \
}

// One block per batch element; persistent scan over all T steps.
// 512 threads: hex = tid&15 owns k-rows 16*hex..16*hex+15 (and x 4*hex..+3);
// cg = tid>>4 owns columns 8cg..8cg+7 (weights in registers as column-pair
// f2 vectors -> v_pk_fma_f32). hy broadcast via 2.5 KB double-buffered LDS;
// x loaded per-thread from global (L1-hot); outputs stored directly to
// global (coalesced 128B per wave per array).
__global__ __launch_bounds__(512, 2) void ron_scan(
    const float* __restrict__ x, const float* __restrict__ h2h,
    const float* __restrict__ x2h, float* __restrict__ out)
{
    // 16 sections of 16 floats, stride 20: section starts at banks
    // {0,20,8,28,16,4,24,12} x2 -> worst 2-way aliasing (free, m136).
    __shared__ __align__(16) float hyb[2][320];

    const int tid = threadIdx.x;
    const int hex = tid & 15;
    const int cg  = tid >> 4;              // 0..31
    const int b   = blockIdx.x;
    const int bT  = b * T_;
    const int col = 8 * cg + (hex & 7);    // column this lane's sums land on
    const bool b0 = hex & 1, b1 = hex & 2, b2 = hex & 4;

    // ---- stage weights into registers as column-pair f2 vectors ----
    f2 ha01[16], ha23[16], ha45[16], ha67[16];
    f2 xa01[4], xa23[4], xa45[4], xa67[4];
#pragma unroll
    for (int i = 0; i < 16; ++i) {
        float4 vA = *(const float4*)&h2h[(16 * hex + i) * NH + 8 * cg];
        float4 vB = *(const float4*)&h2h[(16 * hex + i) * NH + 8 * cg + 4];
        ha01[i] = (f2){vA.x, vA.y}; ha23[i] = (f2){vA.z, vA.w};
        ha45[i] = (f2){vB.x, vB.y}; ha67[i] = (f2){vB.z, vB.w};
    }
#pragma unroll
    for (int i = 0; i < 4; ++i) {
        float4 vA = *(const float4*)&x2h[(4 * hex + i) * NH + 8 * cg];
        float4 vB = *(const float4*)&x2h[(4 * hex + i) * NH + 8 * cg + 4];
        xa01[i] = (f2){vA.x, vA.y}; xa23[i] = (f2){vA.z, vA.w};
        xa45[i] = (f2){vB.x, vB.y}; xa67[i] = (f2){vB.z, vB.w};
    }

    if (tid < 320) ((float*)hyb)[tid] = 0.0f;   // hyb[0] = 0 (t=0 state)
    __syncthreads();

    // LDS pointers: reads at section hex; writes at owned col's slot.
    const float* const rs0 = &hyb[0][20 * hex];
    const float* const rs1 = &hyb[1][20 * hex];
    float* const wA = &hyb[1][20 * (col >> 4) + (col & 15)];  // used when P=0
    float* const wB = &hyb[0][20 * (col >> 4) + (col & 15)];  // used when P=1

    float u = 0.f, hz = 0.f, hy = 0.f;
    float4 xcur = *(const float4*)&x[(size_t)bT * NI + 4 * hex];

    for (int t = 0; t < T_; t += 2) {
        STEP(0, t)
        STEP(1, t + 1)
    }
}

extern "C" void kernel_launch(void* const* d_in, const int* in_sizes, int n_in,
                              void* d_out, int out_size, void* d_ws, size_t ws_size,
                              hipStream_t stream) {
    const float* x   = (const float*)d_in[0];
    const float* h2h = (const float*)d_in[1];
    const float* x2h = (const float*)d_in[2];
    float* out = (float*)d_out;
    ron_scan<<<B_, 512, 0, stream>>>(x, h2h, x2h, out);
}